// Round 4
// baseline (331.644 us; speedup 1.0000x reference)
//
#include <hip/hip_runtime.h>

#define N_NODES 50000
#define N_EDGES 800000

typedef float f32x4 __attribute__((ext_vector_type(4)));
typedef __bf16 bf16x8 __attribute__((ext_vector_type(8)));
typedef __bf16 bf16x4 __attribute__((ext_vector_type(4)));

// ---------------- graph preprocessing ----------------

__global__ void hist_kernel(const int* __restrict__ dst, int* __restrict__ deg, int E) {
    int e = blockIdx.x * blockDim.x + threadIdx.x;
    if (e < E) atomicAdd(&deg[dst[e]], 1);
}

__device__ __forceinline__ int wave_incl_scan(int x) {
    int lane = threadIdx.x & 63;
#pragma unroll
    for (int off = 1; off < 64; off <<= 1) {
        int y = __shfl_up(x, off, 64);
        if (lane >= off) x += y;
    }
    return x;
}

// exclusive-scan partials over 512-chunks; also emits dinv = rsqrt(deg+1)
__global__ void scan_partial_dinv(const int* __restrict__ in, int n,
                                  int* __restrict__ out_partial, int* __restrict__ blocksum,
                                  float* __restrict__ dinv) {
    __shared__ int wsum[8];
    int i = blockIdx.x * 512 + threadIdx.x;
    int v = (i < n) ? in[i] : 0;
    if (i < n) dinv[i] = rsqrtf((float)(v + 1));  // +1 self-loop
    int inc = wave_incl_scan(v);
    int lane = threadIdx.x & 63, wid = threadIdx.x >> 6;
    if (lane == 63) wsum[wid] = inc;
    __syncthreads();
    if (wid == 0) {
        int w = (lane < 8) ? wsum[lane] : 0;
        int wi = wave_incl_scan(w);
        if (lane < 8) wsum[lane] = wi;
    }
    __syncthreads();
    int woff = (wid == 0) ? 0 : wsum[wid - 1];
    if (i < n) out_partial[i] = woff + inc - v;
    if (threadIdx.x == 0) blocksum[blockIdx.x] = wsum[7];
}

__global__ void scan_small(const int* __restrict__ in, int nb, int* __restrict__ out) {
    __shared__ int wsum[2];
    int i = threadIdx.x;
    int v = (i < nb) ? in[i] : 0;
    int inc = wave_incl_scan(v);
    int lane = threadIdx.x & 63, wid = threadIdx.x >> 6;
    if (lane == 63) wsum[wid] = inc;
    __syncthreads();
    int woff = (wid == 0) ? 0 : wsum[0];
    if (i < nb) out[i] = woff + inc - v;
}

__global__ void scan_add(int* __restrict__ rowptr, int n, const int* __restrict__ blockoff, int total) {
    int i = blockIdx.x * 512 + threadIdx.x;
    if (i < n) rowptr[i] += blockoff[blockIdx.x];
    if (i == 0) rowptr[n] = total;
}

__global__ void fill_csr(const int* __restrict__ src, const int* __restrict__ dst, int E,
                         const int* __restrict__ rowptr, int* __restrict__ cursor,
                         int* __restrict__ csr_src) {
    int e = blockIdx.x * blockDim.x + threadIdx.x;
    if (e < E) {
        int d = dst[e];
        int pos = rowptr[d] + atomicAdd(&cursor[d], 1);
        csr_src[pos] = src[e];
    }
}

// sort each row's src list ascending (locality: concurrent waves walk src space
// in percentile order -> clustered L2 window; also makes CSR deterministic)
__global__ void sort_rows(const int* __restrict__ rowptr, int* __restrict__ csr, int n) {
    int i = blockIdx.x * blockDim.x + threadIdx.x;
    if (i >= n) return;
    int b = rowptr[i], e = rowptr[i + 1];
    for (int j = b + 1; j < e; ++j) {
        int v = csr[j], k = j - 1;
        while (k >= b && csr[k] > v) { csr[k + 1] = csr[k]; --k; }
        csr[k + 1] = v;
    }
}

// ---------------- casts / weight prep ----------------

__global__ void cast_scale_kernel(const float* __restrict__ in, const float* __restrict__ dinv,
                                  __bf16* __restrict__ x_bf, __bf16* __restrict__ x_s, int n4) {
    int i = blockIdx.x * blockDim.x + threadIdx.x;
    if (i < n4) {
        float4 v = ((const float4*)in)[i];
        float di = dinv[i >> 5];  // 32 float4 per 128-wide row
        bf16x4 a = {(__bf16)v.x, (__bf16)v.y, (__bf16)v.z, (__bf16)v.w};
        bf16x4 s = {(__bf16)(di * v.x), (__bf16)(di * v.y), (__bf16)(di * v.z), (__bf16)(di * v.w)};
        ((bf16x4*)x_bf)[i] = a;
        ((bf16x4*)x_s)[i] = s;
    }
}

// all 4 weight transposes + final-bias add in one dispatch
__global__ void prep_weights(const float* __restrict__ W1, const float* __restrict__ W2,
                             const float* __restrict__ Wf, const float* __restrict__ Ws,
                             const float* __restrict__ bfb, const float* __restrict__ bsb,
                             __bf16* __restrict__ W1t, __bf16* __restrict__ W2t,
                             __bf16* __restrict__ Wft, __bf16* __restrict__ Wst,
                             float* __restrict__ bfinal) {
    int idx = blockIdx.x * blockDim.x + threadIdx.x;
    if (idx < 32768) {                       // W1t[n*128+k] = W1[k*256+n]
        int n = idx >> 7, k = idx & 127;
        W1t[idx] = (__bf16)W1[k * 256 + n];
    } else if (idx < 32768 + 65536) {        // W2t[n*256+k] = W2[k*256+n]
        int i = idx - 32768;
        int n = i >> 8, k = i & 255;
        W2t[i] = (__bf16)W2[k * 256 + n];
    } else if (idx < 32768 + 65536 + 16384) {  // Wft[n*256+k] = Wf[k*64+n]
        int i = idx - (32768 + 65536);
        int n = i >> 8, k = i & 255;
        Wft[i] = (__bf16)Wf[k * 64 + n];
    } else if (idx < 32768 + 65536 + 16384 + 8192) {  // Wst[n*128+k] = Ws[k*64+n]
        int i = idx - (32768 + 65536 + 16384);
        int n = i >> 7, k = i & 127;
        Wst[i] = (__bf16)Ws[k * 64 + n];
    } else if (idx < 32768 + 65536 + 16384 + 8192 + 64) {
        int i = idx - (32768 + 65536 + 16384 + 8192);
        bfinal[i] = bfb[i] + bsb[i];
    }
}

// ---------------- aggregation: out[i] = dinv[i]*(in_s[i] + sum_e in_s[s]) ----------------
// Half-wave layout: 32 lanes x 16B(F=256)/8B(F=128) cover one row; each load
// instruction gathers TWO edges' rows (lanes 0-31 -> edge e, 32-63 -> e+1).
// Unroll 8 edges/iter = 4 KB in flight per wave. Halves merged via shfl_xor(32).

template <int V> struct VecSel;
template <> struct VecSel<4> { using T = bf16x4; };
template <> struct VecSel<8> { using T = bf16x8; };

template <int F>
__global__ __launch_bounds__(256) void aggregate_half(const __bf16* __restrict__ in_s, __bf16* __restrict__ out,
                                                      const int* __restrict__ rowptr, const int* __restrict__ csr_src,
                                                      const float* __restrict__ dinv) {
    constexpr int VB = F / 32;  // elems per lane within a half-wave row
    using VT = typename VecSel<VB>::T;
    int node = blockIdx.x * 4 + (threadIdx.x >> 6);
    int lane = threadIdx.x & 63;
    int lh = lane & 31;
    int half = lane >> 5;
    const __bf16* colbase = in_s + (size_t)lh * VB;

    float acc[VB] = {};
    if (half == 0) {  // self-loop row loaded by half A only
        VT v = *(const VT*)(colbase + (size_t)node * F);
#pragma unroll
        for (int j = 0; j < VB; ++j) acc[j] = (float)v[j];
    }

    int beg = rowptr[node], end = rowptr[node + 1];
    int e = beg;
    for (; e + 8 <= end; e += 8) {
        int a0 = csr_src[e + 0], a1 = csr_src[e + 1], a2 = csr_src[e + 2], a3 = csr_src[e + 3];
        int a4 = csr_src[e + 4], a5 = csr_src[e + 5], a6 = csr_src[e + 6], a7 = csr_src[e + 7];
        int s0 = half ? a1 : a0, s1 = half ? a3 : a2, s2 = half ? a5 : a4, s3 = half ? a7 : a6;
        VT v0 = *(const VT*)(colbase + (size_t)s0 * F);
        VT v1 = *(const VT*)(colbase + (size_t)s1 * F);
        VT v2 = *(const VT*)(colbase + (size_t)s2 * F);
        VT v3 = *(const VT*)(colbase + (size_t)s3 * F);
#pragma unroll
        for (int j = 0; j < VB; ++j) {
            acc[j] += (float)v0[j];
            acc[j] += (float)v1[j];
            acc[j] += (float)v2[j];
            acc[j] += (float)v3[j];
        }
    }
    for (; e + 2 <= end; e += 2) {
        int a0 = csr_src[e], a1 = csr_src[e + 1];
        int s = half ? a1 : a0;
        VT v = *(const VT*)(colbase + (size_t)s * F);
#pragma unroll
        for (int j = 0; j < VB; ++j) acc[j] += (float)v[j];
    }
    if (e < end && half == 0) {  // odd tail: half A only
        int s = csr_src[e];
        VT v = *(const VT*)(colbase + (size_t)s * F);
#pragma unroll
        for (int j = 0; j < VB; ++j) acc[j] += (float)v[j];
    }

    float di = dinv[node];
    VT o;
#pragma unroll
    for (int j = 0; j < VB; ++j) {
        float t = acc[j] + __shfl_xor(acc[j], 32);
        o[j] = (__bf16)(di * t);
    }
    if (half == 0) *(VT*)(out + (size_t)node * F + lh * VB) = o;
}

// ---------------- MFMA bf16 GEMM staging (shared) ----------------
// LDS rows of 64 bf16 (8 x 16B granules), granule slot XOR-swizzled with (row&7).
// global_load_lds writes linearly; global SOURCE address pre-swizzled with the same
// involution so the swizzled read matches (rule 21).

template <int NROWS, int NTH>
__device__ __forceinline__ void stage_tile(const __bf16* __restrict__ src, int K, int row0, int rowclamp,
                                           int k0, char* lds) {
    int t = threadIdx.x;
#pragma unroll
    for (int p = 0; p < NROWS * 8 / NTH; ++p) {
        int G = p * NTH + t;
        int r = G >> 3, gp = G & 7;
        int g = gp ^ (r & 7);
        int gr = row0 + r;
        if (gr > rowclamp) gr = rowclamp;
        const __bf16* sp = src + (size_t)gr * K + k0 + g * 8;
        __builtin_amdgcn_global_load_lds((const __attribute__((address_space(1))) void*)sp,
                                         (__attribute__((address_space(3))) void*)(lds + G * 16), 16, 0, 0);
    }
}

// ---------------- wide GEMM: C[M x 256] = A[M x K] * Bt[256 x K]^T, BM=128, 8 waves ----------------

template <bool SCALE>
__global__ __launch_bounds__(512) void mfma_gemm_wide(const __bf16* __restrict__ A, const __bf16* __restrict__ Bt,
                                                      int K, const float* __restrict__ bias,
                                                      const float* __restrict__ dinv,
                                                      __bf16* __restrict__ C, int M) {
    constexpr int N = 256;
    __shared__ alignas(16) char lds[49152];  // A: 128x64 = 16 KB, B: 256x64 = 32 KB
    char* As = lds;
    char* Bs = lds + 16384;
    const int lane = threadIdx.x & 63, wid = threadIdx.x >> 6;
    const int wm = wid >> 2, wn = wid & 3;  // 2 x 4 waves, wave tile 64x64
    const int row0 = blockIdx.x * 128;
    const int kg = lane >> 4, l15 = lane & 15;

    f32x4 acc[4][4];
#pragma unroll
    for (int mi = 0; mi < 4; ++mi)
#pragma unroll
        for (int ni = 0; ni < 4; ++ni) acc[mi][ni] = {0.f, 0.f, 0.f, 0.f};

    for (int k0 = 0; k0 < K; k0 += 64) {
        stage_tile<128, 512>(A, K, row0, M - 1, k0, As);
        stage_tile<256, 512>(Bt, K, 0, N - 1, k0, Bs);
        __syncthreads();
        bf16x8 af[4][2], bfr[4][2];
#pragma unroll
        for (int mi = 0; mi < 4; ++mi) {
            int r = wm * 64 + mi * 16 + l15;
#pragma unroll
            for (int kf = 0; kf < 2; ++kf) {
                int slot = (kf * 4 + kg) ^ (r & 7);
                af[mi][kf] = *(const bf16x8*)(As + r * 128 + slot * 16);
            }
        }
#pragma unroll
        for (int ni = 0; ni < 4; ++ni) {
            int r = wn * 64 + ni * 16 + l15;
#pragma unroll
            for (int kf = 0; kf < 2; ++kf) {
                int slot = (kf * 4 + kg) ^ (r & 7);
                bfr[ni][kf] = *(const bf16x8*)(Bs + r * 128 + slot * 16);
            }
        }
#pragma unroll
        for (int mi = 0; mi < 4; ++mi)
#pragma unroll
            for (int ni = 0; ni < 4; ++ni)
#pragma unroll
                for (int kf = 0; kf < 2; ++kf)
                    acc[mi][ni] = __builtin_amdgcn_mfma_f32_16x16x32_bf16(af[mi][kf], bfr[ni][kf],
                                                                          acc[mi][ni], 0, 0, 0);
        __syncthreads();
    }

    // C/D layout: col = lane&15, row = (lane>>4)*4 + q
#pragma unroll
    for (int mi = 0; mi < 4; ++mi) {
#pragma unroll
        for (int q = 0; q < 4; ++q) {
            int gr = row0 + wm * 64 + mi * 16 + kg * 4 + q;
            if (gr >= M) continue;
            float sc = SCALE ? dinv[gr] : 1.0f;
#pragma unroll
            for (int ni = 0; ni < 4; ++ni) {
                int col = wn * 64 + ni * 16 + l15;
                float v = acc[mi][ni][q] + bias[col];
                v = fmaxf(v, 0.f);  // both uses are relu layers
                if (SCALE) v *= sc;
                C[(size_t)gr * N + col] = (__bf16)v;
            }
        }
    }
}

// ---------------- final GEMM: out[M x 64] = A1*B1t^T + A2*B2t^T + bias (f32 out) ----------------

__global__ __launch_bounds__(256) void mfma_gemm_final(const __bf16* __restrict__ A1, const __bf16* __restrict__ B1t, int K1,
                                                       const __bf16* __restrict__ A2, const __bf16* __restrict__ B2t, int K2,
                                                       const float* __restrict__ bias, float* __restrict__ Cout, int M) {
    constexpr int N = 64;
    __shared__ alignas(16) char lds[24576];
    char* As = lds;
    char* Bs = lds + 16384;
    const int lane = threadIdx.x & 63, wid = threadIdx.x >> 6;
    const int wm = wid >> 1, wn = wid & 1;
    const int row0 = blockIdx.x * 128;
    const int kg = lane >> 4, l15 = lane & 15;

    f32x4 acc[4][2];
#pragma unroll
    for (int mi = 0; mi < 4; ++mi)
#pragma unroll
        for (int ni = 0; ni < 2; ++ni) acc[mi][ni] = {0.f, 0.f, 0.f, 0.f};

    auto run_K = [&](const __bf16* A, const __bf16* Bt, int K) {
        for (int k0 = 0; k0 < K; k0 += 64) {
            stage_tile<128, 256>(A, K, row0, M - 1, k0, As);
            stage_tile<64, 256>(Bt, K, 0, N - 1, k0, Bs);
            __syncthreads();
            bf16x8 af[4][2], bfr[2][2];
#pragma unroll
            for (int mi = 0; mi < 4; ++mi) {
                int r = wm * 64 + mi * 16 + l15;
#pragma unroll
                for (int kf = 0; kf < 2; ++kf) {
                    int slot = (kf * 4 + kg) ^ (r & 7);
                    af[mi][kf] = *(const bf16x8*)(As + r * 128 + slot * 16);
                }
            }
#pragma unroll
            for (int ni = 0; ni < 2; ++ni) {
                int r = wn * 32 + ni * 16 + l15;
#pragma unroll
                for (int kf = 0; kf < 2; ++kf) {
                    int slot = (kf * 4 + kg) ^ (r & 7);
                    bfr[ni][kf] = *(const bf16x8*)(Bs + r * 128 + slot * 16);
                }
            }
#pragma unroll
            for (int mi = 0; mi < 4; ++mi)
#pragma unroll
                for (int ni = 0; ni < 2; ++ni)
#pragma unroll
                    for (int kf = 0; kf < 2; ++kf)
                        acc[mi][ni] = __builtin_amdgcn_mfma_f32_16x16x32_bf16(af[mi][kf], bfr[ni][kf],
                                                                              acc[mi][ni], 0, 0, 0);
            __syncthreads();
        }
    };
    run_K(A1, B1t, K1);
    run_K(A2, B2t, K2);

#pragma unroll
    for (int mi = 0; mi < 4; ++mi) {
#pragma unroll
        for (int ni = 0; ni < 2; ++ni) {
            int col = wn * 32 + ni * 16 + l15;
            float bv = bias[col];
#pragma unroll
            for (int q = 0; q < 4; ++q) {
                int gr = row0 + wm * 64 + mi * 16 + kg * 4 + q;
                if (gr < M) Cout[(size_t)gr * N + col] = acc[mi][ni][q] + bv;
            }
        }
    }
}

// ---------------- launch ----------------

extern "C" void kernel_launch(void* const* d_in, const int* in_sizes, int n_in,
                              void* d_out, int out_size, void* d_ws, size_t ws_size,
                              hipStream_t stream) {
    const float* x  = (const float*)d_in[0];
    const int*   ei = (const int*)d_in[1];
    const int*   src = ei;
    const int*   dst = ei + N_EDGES;
    const float* W1 = (const float*)d_in[2];
    const float* b1 = (const float*)d_in[3];
    const float* W2 = (const float*)d_in[4];
    const float* b2 = (const float*)d_in[5];
    const float* Wf = (const float*)d_in[6];
    const float* bf = (const float*)d_in[7];
    const float* Ws = (const float*)d_in[8];
    const float* bs = (const float*)d_in[9];
    float* out = (float*)d_out;

    char* ws = (char*)d_ws;
    size_t off = 0;
    auto alloc = [&](size_t bytes) -> void* {
        void* p = ws + off;
        off += (bytes + 255) & ~(size_t)255;
        return p;
    };
    int*     deg      = (int*)alloc(N_NODES * 4);   // adjacent to cursor: one memset covers both
    int*     cursor   = (int*)alloc(N_NODES * 4);
    int*     rowptr   = (int*)alloc((N_NODES + 1) * 4);
    float*   dinv     = (float*)alloc(N_NODES * 4);
    int*     blocksum = (int*)alloc(4096);
    int*     blockoff = (int*)alloc(4096);
    int*     csr      = (int*)alloc(N_EDGES * 4);
    __bf16*  x_bf     = (__bf16*)alloc((size_t)N_NODES * 128 * 2);  // unscaled (skip GEMM)
    __bf16*  x_s      = (__bf16*)alloc((size_t)N_NODES * 128 * 2);  // dinv-scaled (agg1 input)
    __bf16*  W1t      = (__bf16*)alloc(128 * 256 * 2);
    __bf16*  W2t      = (__bf16*)alloc(256 * 256 * 2);
    __bf16*  Wft      = (__bf16*)alloc(256 * 64 * 2);
    __bf16*  Wst      = (__bf16*)alloc(128 * 64 * 2);
    float*   bfinal   = (float*)alloc(64 * 4);
    __bf16*  bufP1    = (__bf16*)alloc((size_t)N_NODES * 256 * 2);  // agg1 out (128-wide), later h2
    __bf16*  bufP2    = (__bf16*)alloc((size_t)N_NODES * 256 * 2);  // h1_s
    __bf16*  bufP3    = (__bf16*)alloc((size_t)N_NODES * 256 * 2);  // agg2 out

    // deg (200192 padded) + cursor (200192 padded) in one memset
    hipMemsetAsync(deg, 0, 200192 + 200192, stream);

    hist_kernel<<<(N_EDGES + 255) / 256, 256, 0, stream>>>(dst, deg, N_EDGES);

    int nb = (N_NODES + 511) / 512;  // 98
    scan_partial_dinv<<<nb, 512, 0, stream>>>(deg, N_NODES, rowptr, blocksum, dinv);
    scan_small<<<1, 128, 0, stream>>>(blocksum, nb, blockoff);
    scan_add<<<nb, 512, 0, stream>>>(rowptr, N_NODES, blockoff, N_EDGES);
    fill_csr<<<(N_EDGES + 255) / 256, 256, 0, stream>>>(src, dst, N_EDGES, rowptr, cursor, csr);
    sort_rows<<<(N_NODES + 255) / 256, 256, 0, stream>>>(rowptr, csr, N_NODES);

    cast_scale_kernel<<<(N_NODES * 128 / 4 + 255) / 256, 256, 0, stream>>>(x, dinv, x_bf, x_s, N_NODES * 128 / 4);
    prep_weights<<<(32768 + 65536 + 16384 + 8192 + 64 + 255) / 256, 256, 0, stream>>>(
        W1, W2, Wf, Ws, bf, bs, W1t, W2t, Wft, Wst, bfinal);

    const int gm = (N_NODES + 127) / 128;  // 391

    // layer 1: agg1 = Ahat x (pre-scaled x_s); h1_s = dinv * relu(agg1 @ W1 + b1)
    aggregate_half<128><<<(N_NODES + 3) / 4, 256, 0, stream>>>(x_s, bufP1, rowptr, csr, dinv);
    mfma_gemm_wide<true><<<gm, 512, 0, stream>>>(bufP1, W1t, 128, b1, dinv, bufP2, N_NODES);

    // layer 2: agg2 = dinv * (sum of h1_s + self); h2 = relu(agg2 @ W2 + b2)
    aggregate_half<256><<<(N_NODES + 3) / 4, 256, 0, stream>>>(bufP2, bufP3, rowptr, csr, dinv);
    mfma_gemm_wide<false><<<gm, 512, 0, stream>>>(bufP3, W2t, 256, b2, nullptr, bufP1, N_NODES);

    // out = h2 @ Wf + x @ Ws + (bf + bs)
    mfma_gemm_final<<<gm, 256, 0, stream>>>(bufP1, Wft, 256, x_bf, Wst, 128, bfinal, out, N_NODES);
}

// Round 5
// 258.675 us; speedup vs baseline: 1.2821x; 1.2821x over previous
//
#include <hip/hip_runtime.h>

#define N_NODES 50000
#define N_EDGES 800000

typedef float f32x4 __attribute__((ext_vector_type(4)));
typedef __bf16 bf16x8 __attribute__((ext_vector_type(8)));
typedef __bf16 bf16x4 __attribute__((ext_vector_type(4)));

// ---------------- graph preprocessing ----------------

__global__ void hist_kernel(const int* __restrict__ dst, int* __restrict__ deg, int E) {
    int e = blockIdx.x * blockDim.x + threadIdx.x;
    if (e < E) atomicAdd(&deg[dst[e]], 1);
}

__device__ __forceinline__ int wave_incl_scan(int x) {
    int lane = threadIdx.x & 63;
#pragma unroll
    for (int off = 1; off < 64; off <<= 1) {
        int y = __shfl_up(x, off, 64);
        if (lane >= off) x += y;
    }
    return x;
}

// exclusive-scan partials over 512-chunks; also emits dinv = rsqrt(deg+1)
__global__ void scan_partial_dinv(const int* __restrict__ in, int n,
                                  int* __restrict__ out_partial, int* __restrict__ blocksum,
                                  float* __restrict__ dinv) {
    __shared__ int wsum[8];
    int i = blockIdx.x * 512 + threadIdx.x;
    int v = (i < n) ? in[i] : 0;
    if (i < n) dinv[i] = rsqrtf((float)(v + 1));  // +1 self-loop
    int inc = wave_incl_scan(v);
    int lane = threadIdx.x & 63, wid = threadIdx.x >> 6;
    if (lane == 63) wsum[wid] = inc;
    __syncthreads();
    if (wid == 0) {
        int w = (lane < 8) ? wsum[lane] : 0;
        int wi = wave_incl_scan(w);
        if (lane < 8) wsum[lane] = wi;
    }
    __syncthreads();
    int woff = (wid == 0) ? 0 : wsum[wid - 1];
    if (i < n) out_partial[i] = woff + inc - v;
    if (threadIdx.x == 0) blocksum[blockIdx.x] = wsum[7];
}

__global__ void scan_small(const int* __restrict__ in, int nb, int* __restrict__ out) {
    __shared__ int wsum[2];
    int i = threadIdx.x;
    int v = (i < nb) ? in[i] : 0;
    int inc = wave_incl_scan(v);
    int lane = threadIdx.x & 63, wid = threadIdx.x >> 6;
    if (lane == 63) wsum[wid] = inc;
    __syncthreads();
    int woff = (wid == 0) ? 0 : wsum[0];
    if (i < nb) out[i] = woff + inc - v;
}

__global__ void scan_add(int* __restrict__ rowptr, int n, const int* __restrict__ blockoff, int total) {
    int i = blockIdx.x * 512 + threadIdx.x;
    if (i < n) rowptr[i] += blockoff[blockIdx.x];
    if (i == 0) rowptr[n] = total;
}

__global__ void fill_csr(const int* __restrict__ src, const int* __restrict__ dst, int E,
                         const int* __restrict__ rowptr, int* __restrict__ cursor,
                         int* __restrict__ csr_src) {
    int e = blockIdx.x * blockDim.x + threadIdx.x;
    if (e < E) {
        int d = dst[e];
        int pos = rowptr[d] + atomicAdd(&cursor[d], 1);
        csr_src[pos] = src[e];
    }
}

// sort each row ascending: one WAVE per node, 64-element bitonic network in
// registers via shfl_xor (deg>64 is ~impossible for Binomial(800k,1/50k);
// lane-0 serial fallback for safety). Locality: concurrent waves walk src
// space in percentile order -> clustered L2 window; also deterministic CSR.
__global__ __launch_bounds__(256) void sort_rows_wave(const int* __restrict__ rowptr,
                                                      int* __restrict__ csr, int n) {
    int node = blockIdx.x * 4 + (threadIdx.x >> 6);
    if (node >= n) return;
    int lane = threadIdx.x & 63;
    int b = rowptr[node], e = rowptr[node + 1];
    int d = e - b;
    if (d <= 1) return;
    if (d <= 64) {
        int v = (lane < d) ? csr[b + lane] : 0x7fffffff;
#pragma unroll
        for (int k = 2; k <= 64; k <<= 1) {
#pragma unroll
            for (int j = k >> 1; j > 0; j >>= 1) {
                int w = __shfl_xor(v, j, 64);
                bool up = ((lane & k) == 0);       // ascending block
                bool lower = ((lane & j) == 0);
                v = (lower == up) ? min(v, w) : max(v, w);
            }
        }
        if (lane < d) csr[b + lane] = v;
    } else if (lane == 0) {
        for (int j = b + 1; j < e; ++j) {
            int v = csr[j], k = j - 1;
            while (k >= b && csr[k] > v) { csr[k + 1] = csr[k]; --k; }
            csr[k + 1] = v;
        }
    }
}

// ---------------- casts / weight prep ----------------

__global__ void cast_scale_kernel(const float* __restrict__ in, const float* __restrict__ dinv,
                                  __bf16* __restrict__ x_bf, __bf16* __restrict__ x_s, int n4) {
    int i = blockIdx.x * blockDim.x + threadIdx.x;
    if (i < n4) {
        float4 v = ((const float4*)in)[i];
        float di = dinv[i >> 5];  // 32 float4 per 128-wide row
        bf16x4 a = {(__bf16)v.x, (__bf16)v.y, (__bf16)v.z, (__bf16)v.w};
        bf16x4 s = {(__bf16)(di * v.x), (__bf16)(di * v.y), (__bf16)(di * v.z), (__bf16)(di * v.w)};
        ((bf16x4*)x_bf)[i] = a;
        ((bf16x4*)x_s)[i] = s;
    }
}

// all 4 weight transposes + final-bias add in one dispatch
__global__ void prep_weights(const float* __restrict__ W1, const float* __restrict__ W2,
                             const float* __restrict__ Wf, const float* __restrict__ Ws,
                             const float* __restrict__ bfb, const float* __restrict__ bsb,
                             __bf16* __restrict__ W1t, __bf16* __restrict__ W2t,
                             __bf16* __restrict__ Wft, __bf16* __restrict__ Wst,
                             float* __restrict__ bfinal) {
    int idx = blockIdx.x * blockDim.x + threadIdx.x;
    if (idx < 32768) {                       // W1t[n*128+k] = W1[k*256+n]
        int n = idx >> 7, k = idx & 127;
        W1t[idx] = (__bf16)W1[k * 256 + n];
    } else if (idx < 32768 + 65536) {        // W2t[n*256+k] = W2[k*256+n]
        int i = idx - 32768;
        int n = i >> 8, k = i & 255;
        W2t[i] = (__bf16)W2[k * 256 + n];
    } else if (idx < 32768 + 65536 + 16384) {  // Wft[n*256+k] = Wf[k*64+n]
        int i = idx - (32768 + 65536);
        int n = i >> 8, k = i & 255;
        Wft[i] = (__bf16)Wf[k * 64 + n];
    } else if (idx < 32768 + 65536 + 16384 + 8192) {  // Wst[n*128+k] = Ws[k*64+n]
        int i = idx - (32768 + 65536 + 16384);
        int n = i >> 7, k = i & 127;
        Wst[i] = (__bf16)Ws[k * 64 + n];
    } else if (idx < 32768 + 65536 + 16384 + 8192 + 64) {
        int i = idx - (32768 + 65536 + 16384 + 8192);
        bfinal[i] = bfb[i] + bsb[i];
    }
}

// ---------------- aggregation: out[i] = dinv[i]*(in_s[i] + sum_e in_s[s]) ----------------
// Half-wave layout: 32 lanes x 16B(F=256)/8B(F=128) cover one row; each load
// instruction gathers TWO edges' rows (lanes 0-31 -> edge e, 32-63 -> e+1).
// Unroll 8 edges/iter = 4 KB in flight per wave. Halves merged via shfl_xor(32).

template <int V> struct VecSel;
template <> struct VecSel<4> { using T = bf16x4; };
template <> struct VecSel<8> { using T = bf16x8; };

template <int F>
__global__ __launch_bounds__(256) void aggregate_half(const __bf16* __restrict__ in_s, __bf16* __restrict__ out,
                                                      const int* __restrict__ rowptr, const int* __restrict__ csr_src,
                                                      const float* __restrict__ dinv) {
    constexpr int VB = F / 32;  // elems per lane within a half-wave row
    using VT = typename VecSel<VB>::T;
    int node = blockIdx.x * 4 + (threadIdx.x >> 6);
    int lane = threadIdx.x & 63;
    int lh = lane & 31;
    int half = lane >> 5;
    const __bf16* colbase = in_s + (size_t)lh * VB;

    float acc[VB] = {};
    if (half == 0) {  // self-loop row loaded by half A only
        VT v = *(const VT*)(colbase + (size_t)node * F);
#pragma unroll
        for (int j = 0; j < VB; ++j) acc[j] = (float)v[j];
    }

    int beg = rowptr[node], end = rowptr[node + 1];
    int e = beg;
    for (; e + 8 <= end; e += 8) {
        int a0 = csr_src[e + 0], a1 = csr_src[e + 1], a2 = csr_src[e + 2], a3 = csr_src[e + 3];
        int a4 = csr_src[e + 4], a5 = csr_src[e + 5], a6 = csr_src[e + 6], a7 = csr_src[e + 7];
        int s0 = half ? a1 : a0, s1 = half ? a3 : a2, s2 = half ? a5 : a4, s3 = half ? a7 : a6;
        VT v0 = *(const VT*)(colbase + (size_t)s0 * F);
        VT v1 = *(const VT*)(colbase + (size_t)s1 * F);
        VT v2 = *(const VT*)(colbase + (size_t)s2 * F);
        VT v3 = *(const VT*)(colbase + (size_t)s3 * F);
#pragma unroll
        for (int j = 0; j < VB; ++j) {
            acc[j] += (float)v0[j];
            acc[j] += (float)v1[j];
            acc[j] += (float)v2[j];
            acc[j] += (float)v3[j];
        }
    }
    for (; e + 2 <= end; e += 2) {
        int a0 = csr_src[e], a1 = csr_src[e + 1];
        int s = half ? a1 : a0;
        VT v = *(const VT*)(colbase + (size_t)s * F);
#pragma unroll
        for (int j = 0; j < VB; ++j) acc[j] += (float)v[j];
    }
    if (e < end && half == 0) {  // odd tail: half A only
        int s = csr_src[e];
        VT v = *(const VT*)(colbase + (size_t)s * F);
#pragma unroll
        for (int j = 0; j < VB; ++j) acc[j] += (float)v[j];
    }

    float di = dinv[node];
    VT o;
#pragma unroll
    for (int j = 0; j < VB; ++j) {
        float t = acc[j] + __shfl_xor(acc[j], 32);
        o[j] = (__bf16)(di * t);
    }
    if (half == 0) *(VT*)(out + (size_t)node * F + lh * VB) = o;
}

// ---------------- MFMA bf16 GEMM staging (shared) ----------------
// LDS rows of 64 bf16 (8 x 16B granules), granule slot XOR-swizzled with (row&7).
// global_load_lds writes linearly; global SOURCE address pre-swizzled with the same
// involution so the swizzled read matches (rule 21).

template <int NROWS, int NTH>
__device__ __forceinline__ void stage_tile(const __bf16* __restrict__ src, int K, int row0, int rowclamp,
                                           int k0, char* lds) {
    int t = threadIdx.x;
#pragma unroll
    for (int p = 0; p < NROWS * 8 / NTH; ++p) {
        int G = p * NTH + t;
        int r = G >> 3, gp = G & 7;
        int g = gp ^ (r & 7);
        int gr = row0 + r;
        if (gr > rowclamp) gr = rowclamp;
        const __bf16* sp = src + (size_t)gr * K + k0 + g * 8;
        __builtin_amdgcn_global_load_lds((const __attribute__((address_space(1))) void*)sp,
                                         (__attribute__((address_space(3))) void*)(lds + G * 16), 16, 0, 0);
    }
}

// ---------------- wide GEMM: C[M x 256] = A[M x K] * Bt[256 x K]^T, BM=128, 8 waves ----------------

template <bool SCALE>
__global__ __launch_bounds__(512) void mfma_gemm_wide(const __bf16* __restrict__ A, const __bf16* __restrict__ Bt,
                                                      int K, const float* __restrict__ bias,
                                                      const float* __restrict__ dinv,
                                                      __bf16* __restrict__ C, int M) {
    constexpr int N = 256;
    __shared__ alignas(16) char lds[49152];  // A: 128x64 = 16 KB, B: 256x64 = 32 KB
    char* As = lds;
    char* Bs = lds + 16384;
    const int lane = threadIdx.x & 63, wid = threadIdx.x >> 6;
    const int wm = wid >> 2, wn = wid & 3;  // 2 x 4 waves, wave tile 64x64
    const int row0 = blockIdx.x * 128;
    const int kg = lane >> 4, l15 = lane & 15;

    f32x4 acc[4][4];
#pragma unroll
    for (int mi = 0; mi < 4; ++mi)
#pragma unroll
        for (int ni = 0; ni < 4; ++ni) acc[mi][ni] = {0.f, 0.f, 0.f, 0.f};

    for (int k0 = 0; k0 < K; k0 += 64) {
        stage_tile<128, 512>(A, K, row0, M - 1, k0, As);
        stage_tile<256, 512>(Bt, K, 0, N - 1, k0, Bs);
        __syncthreads();
        bf16x8 af[4][2], bfr[4][2];
#pragma unroll
        for (int mi = 0; mi < 4; ++mi) {
            int r = wm * 64 + mi * 16 + l15;
#pragma unroll
            for (int kf = 0; kf < 2; ++kf) {
                int slot = (kf * 4 + kg) ^ (r & 7);
                af[mi][kf] = *(const bf16x8*)(As + r * 128 + slot * 16);
            }
        }
#pragma unroll
        for (int ni = 0; ni < 4; ++ni) {
            int r = wn * 64 + ni * 16 + l15;
#pragma unroll
            for (int kf = 0; kf < 2; ++kf) {
                int slot = (kf * 4 + kg) ^ (r & 7);
                bfr[ni][kf] = *(const bf16x8*)(Bs + r * 128 + slot * 16);
            }
        }
#pragma unroll
        for (int mi = 0; mi < 4; ++mi)
#pragma unroll
            for (int ni = 0; ni < 4; ++ni)
#pragma unroll
                for (int kf = 0; kf < 2; ++kf)
                    acc[mi][ni] = __builtin_amdgcn_mfma_f32_16x16x32_bf16(af[mi][kf], bfr[ni][kf],
                                                                          acc[mi][ni], 0, 0, 0);
        __syncthreads();
    }

    // C/D layout: col = lane&15, row = (lane>>4)*4 + q
#pragma unroll
    for (int mi = 0; mi < 4; ++mi) {
#pragma unroll
        for (int q = 0; q < 4; ++q) {
            int gr = row0 + wm * 64 + mi * 16 + kg * 4 + q;
            if (gr >= M) continue;
            float sc = SCALE ? dinv[gr] : 1.0f;
#pragma unroll
            for (int ni = 0; ni < 4; ++ni) {
                int col = wn * 64 + ni * 16 + l15;
                float v = acc[mi][ni][q] + bias[col];
                v = fmaxf(v, 0.f);  // both uses are relu layers
                if (SCALE) v *= sc;
                C[(size_t)gr * N + col] = (__bf16)v;
            }
        }
    }
}

// ---------------- final GEMM: out[M x 64] = A1*B1t^T + A2*B2t^T + bias (f32 out) ----------------

__global__ __launch_bounds__(256) void mfma_gemm_final(const __bf16* __restrict__ A1, const __bf16* __restrict__ B1t, int K1,
                                                       const __bf16* __restrict__ A2, const __bf16* __restrict__ B2t, int K2,
                                                       const float* __restrict__ bias, float* __restrict__ Cout, int M) {
    constexpr int N = 64;
    __shared__ alignas(16) char lds[24576];
    char* As = lds;
    char* Bs = lds + 16384;
    const int lane = threadIdx.x & 63, wid = threadIdx.x >> 6;
    const int wm = wid >> 1, wn = wid & 1;
    const int row0 = blockIdx.x * 128;
    const int kg = lane >> 4, l15 = lane & 15;

    f32x4 acc[4][2];
#pragma unroll
    for (int mi = 0; mi < 4; ++mi)
#pragma unroll
        for (int ni = 0; ni < 2; ++ni) acc[mi][ni] = {0.f, 0.f, 0.f, 0.f};

    auto run_K = [&](const __bf16* A, const __bf16* Bt, int K) {
        for (int k0 = 0; k0 < K; k0 += 64) {
            stage_tile<128, 256>(A, K, row0, M - 1, k0, As);
            stage_tile<64, 256>(Bt, K, 0, N - 1, k0, Bs);
            __syncthreads();
            bf16x8 af[4][2], bfr[2][2];
#pragma unroll
            for (int mi = 0; mi < 4; ++mi) {
                int r = wm * 64 + mi * 16 + l15;
#pragma unroll
                for (int kf = 0; kf < 2; ++kf) {
                    int slot = (kf * 4 + kg) ^ (r & 7);
                    af[mi][kf] = *(const bf16x8*)(As + r * 128 + slot * 16);
                }
            }
#pragma unroll
            for (int ni = 0; ni < 2; ++ni) {
                int r = wn * 32 + ni * 16 + l15;
#pragma unroll
                for (int kf = 0; kf < 2; ++kf) {
                    int slot = (kf * 4 + kg) ^ (r & 7);
                    bfr[ni][kf] = *(const bf16x8*)(Bs + r * 128 + slot * 16);
                }
            }
#pragma unroll
            for (int mi = 0; mi < 4; ++mi)
#pragma unroll
                for (int ni = 0; ni < 2; ++ni)
#pragma unroll
                    for (int kf = 0; kf < 2; ++kf)
                        acc[mi][ni] = __builtin_amdgcn_mfma_f32_16x16x32_bf16(af[mi][kf], bfr[ni][kf],
                                                                              acc[mi][ni], 0, 0, 0);
            __syncthreads();
        }
    };
    run_K(A1, B1t, K1);
    run_K(A2, B2t, K2);

#pragma unroll
    for (int mi = 0; mi < 4; ++mi) {
#pragma unroll
        for (int ni = 0; ni < 2; ++ni) {
            int col = wn * 32 + ni * 16 + l15;
            float bv = bias[col];
#pragma unroll
            for (int q = 0; q < 4; ++q) {
                int gr = row0 + wm * 64 + mi * 16 + kg * 4 + q;
                if (gr < M) Cout[(size_t)gr * N + col] = acc[mi][ni][q] + bv;
            }
        }
    }
}

// ---------------- launch ----------------

extern "C" void kernel_launch(void* const* d_in, const int* in_sizes, int n_in,
                              void* d_out, int out_size, void* d_ws, size_t ws_size,
                              hipStream_t stream) {
    const float* x  = (const float*)d_in[0];
    const int*   ei = (const int*)d_in[1];
    const int*   src = ei;
    const int*   dst = ei + N_EDGES;
    const float* W1 = (const float*)d_in[2];
    const float* b1 = (const float*)d_in[3];
    const float* W2 = (const float*)d_in[4];
    const float* b2 = (const float*)d_in[5];
    const float* Wf = (const float*)d_in[6];
    const float* bf = (const float*)d_in[7];
    const float* Ws = (const float*)d_in[8];
    const float* bs = (const float*)d_in[9];
    float* out = (float*)d_out;

    char* ws = (char*)d_ws;
    size_t off = 0;
    auto alloc = [&](size_t bytes) -> void* {
        void* p = ws + off;
        off += (bytes + 255) & ~(size_t)255;
        return p;
    };
    int*     deg      = (int*)alloc(N_NODES * 4);   // adjacent to cursor: one memset covers both
    int*     cursor   = (int*)alloc(N_NODES * 4);
    int*     rowptr   = (int*)alloc((N_NODES + 1) * 4);
    float*   dinv     = (float*)alloc(N_NODES * 4);
    int*     blocksum = (int*)alloc(4096);
    int*     blockoff = (int*)alloc(4096);
    int*     csr      = (int*)alloc(N_EDGES * 4);
    __bf16*  x_bf     = (__bf16*)alloc((size_t)N_NODES * 128 * 2);  // unscaled (skip GEMM)
    __bf16*  x_s      = (__bf16*)alloc((size_t)N_NODES * 128 * 2);  // dinv-scaled (agg1 input)
    __bf16*  W1t      = (__bf16*)alloc(128 * 256 * 2);
    __bf16*  W2t      = (__bf16*)alloc(256 * 256 * 2);
    __bf16*  Wft      = (__bf16*)alloc(256 * 64 * 2);
    __bf16*  Wst      = (__bf16*)alloc(128 * 64 * 2);
    float*   bfinal   = (float*)alloc(64 * 4);
    __bf16*  bufP1    = (__bf16*)alloc((size_t)N_NODES * 256 * 2);  // agg1 out (128-wide), later h2
    __bf16*  bufP2    = (__bf16*)alloc((size_t)N_NODES * 256 * 2);  // h1_s
    __bf16*  bufP3    = (__bf16*)alloc((size_t)N_NODES * 256 * 2);  // agg2 out

    // deg (200192 padded) + cursor (200192 padded) in one memset
    hipMemsetAsync(deg, 0, 200192 + 200192, stream);

    hist_kernel<<<(N_EDGES + 255) / 256, 256, 0, stream>>>(dst, deg, N_EDGES);

    int nb = (N_NODES + 511) / 512;  // 98
    scan_partial_dinv<<<nb, 512, 0, stream>>>(deg, N_NODES, rowptr, blocksum, dinv);
    scan_small<<<1, 128, 0, stream>>>(blocksum, nb, blockoff);
    scan_add<<<nb, 512, 0, stream>>>(rowptr, N_NODES, blockoff, N_EDGES);
    fill_csr<<<(N_EDGES + 255) / 256, 256, 0, stream>>>(src, dst, N_EDGES, rowptr, cursor, csr);
    sort_rows_wave<<<(N_NODES + 3) / 4, 256, 0, stream>>>(rowptr, csr, N_NODES);

    cast_scale_kernel<<<(N_NODES * 128 / 4 + 255) / 256, 256, 0, stream>>>(x, dinv, x_bf, x_s, N_NODES * 128 / 4);
    prep_weights<<<(32768 + 65536 + 16384 + 8192 + 64 + 255) / 256, 256, 0, stream>>>(
        W1, W2, Wf, Ws, bf, bs, W1t, W2t, Wft, Wst, bfinal);

    const int gm = (N_NODES + 127) / 128;  // 391

    // layer 1: agg1 = Ahat x (pre-scaled x_s); h1_s = dinv * relu(agg1 @ W1 + b1)
    aggregate_half<128><<<(N_NODES + 3) / 4, 256, 0, stream>>>(x_s, bufP1, rowptr, csr, dinv);
    mfma_gemm_wide<true><<<gm, 512, 0, stream>>>(bufP1, W1t, 128, b1, dinv, bufP2, N_NODES);

    // layer 2: agg2 = dinv * (sum of h1_s + self); h2 = relu(agg2 @ W2 + b2)
    aggregate_half<256><<<(N_NODES + 3) / 4, 256, 0, stream>>>(bufP2, bufP3, rowptr, csr, dinv);
    mfma_gemm_wide<false><<<gm, 512, 0, stream>>>(bufP3, W2t, 256, b2, nullptr, bufP1, N_NODES);

    // out = h2 @ Wf + x @ Ws + (bf + bs)
    mfma_gemm_final<<<gm, 256, 0, stream>>>(bufP1, Wft, 256, x_bf, Wst, 128, bfinal, out, N_NODES);
}

// Round 6
// 251.340 us; speedup vs baseline: 1.3195x; 1.0292x over previous
//
#include <hip/hip_runtime.h>

#define N_NODES 50000
#define N_EDGES 800000

typedef float f32x4 __attribute__((ext_vector_type(4)));
typedef __bf16 bf16x8 __attribute__((ext_vector_type(8)));
typedef __bf16 bf16x4 __attribute__((ext_vector_type(4)));

// ---------------- graph preprocessing ----------------

__global__ void hist_kernel(const int* __restrict__ dst, int* __restrict__ deg, int E) {
    int e = blockIdx.x * blockDim.x + threadIdx.x;
    if (e < E) atomicAdd(&deg[dst[e]], 1);
}

__device__ __forceinline__ int wave_incl_scan(int x) {
    int lane = threadIdx.x & 63;
#pragma unroll
    for (int off = 1; off < 64; off <<= 1) {
        int y = __shfl_up(x, off, 64);
        if (lane >= off) x += y;
    }
    return x;
}

// exclusive-scan partials over 512-chunks; also emits dinv = rsqrt(deg+1)
__global__ void scan_partial_dinv(const int* __restrict__ in, int n,
                                  int* __restrict__ out_partial, int* __restrict__ blocksum,
                                  float* __restrict__ dinv) {
    __shared__ int wsum[8];
    int i = blockIdx.x * 512 + threadIdx.x;
    int v = (i < n) ? in[i] : 0;
    if (i < n) dinv[i] = rsqrtf((float)(v + 1));  // +1 self-loop
    int inc = wave_incl_scan(v);
    int lane = threadIdx.x & 63, wid = threadIdx.x >> 6;
    if (lane == 63) wsum[wid] = inc;
    __syncthreads();
    if (wid == 0) {
        int w = (lane < 8) ? wsum[lane] : 0;
        int wi = wave_incl_scan(w);
        if (lane < 8) wsum[lane] = wi;
    }
    __syncthreads();
    int woff = (wid == 0) ? 0 : wsum[wid - 1];
    if (i < n) out_partial[i] = woff + inc - v;
    if (threadIdx.x == 0) blocksum[blockIdx.x] = wsum[7];
}

// fused: every block scans the (<=128) block sums in LDS, then adds its offset.
__global__ void scan_add_fused(int* __restrict__ rowptr, int n,
                               const int* __restrict__ blocksum, int nb, int total) {
    __shared__ int sexc[128];
    __shared__ int w0tot;
    int t = threadIdx.x;
    if (t < 128) {
        int v = (t < nb) ? blocksum[t] : 0;
        int inc = wave_incl_scan(v);
        sexc[t] = inc - v;  // wave-exclusive
        if (t == 63) w0tot = inc;
    }
    __syncthreads();
    int b = blockIdx.x;
    int boff = sexc[b] + (b >= 64 ? w0tot : 0);
    int i = b * 512 + t;
    if (i < n) rowptr[i] += boff;
    if (i == 0) rowptr[n] = total;
}

__global__ void fill_csr(const int* __restrict__ src, const int* __restrict__ dst, int E,
                         const int* __restrict__ rowptr, int* __restrict__ cursor,
                         int* __restrict__ csr_src) {
    int e = blockIdx.x * blockDim.x + threadIdx.x;
    if (e < E) {
        int d = dst[e];
        int pos = rowptr[d] + atomicAdd(&cursor[d], 1);
        csr_src[pos] = src[e];
    }
}

// ---------------- fused casts + weight prep (one dispatch) ----------------

#define CAST_N4 (N_NODES * 32)  // float4 count of x

__global__ void cast_prep(const float* __restrict__ x, const float* __restrict__ dinv,
                          __bf16* __restrict__ x_bf, __bf16* __restrict__ x_s,
                          const float* __restrict__ W1, const float* __restrict__ W2,
                          const float* __restrict__ Wf, const float* __restrict__ Ws,
                          const float* __restrict__ bfb, const float* __restrict__ bsb,
                          __bf16* __restrict__ W1t, __bf16* __restrict__ W2t,
                          __bf16* __restrict__ Wft, __bf16* __restrict__ Wst,
                          float* __restrict__ bfinal) {
    int idx = blockIdx.x * blockDim.x + threadIdx.x;
    if (idx < CAST_N4) {
        float4 v = ((const float4*)x)[idx];
        float di = dinv[idx >> 5];  // 32 float4 per 128-wide row
        bf16x4 a = {(__bf16)v.x, (__bf16)v.y, (__bf16)v.z, (__bf16)v.w};
        bf16x4 s = {(__bf16)(di * v.x), (__bf16)(di * v.y), (__bf16)(di * v.z), (__bf16)(di * v.w)};
        __builtin_nontemporal_store(a, (bf16x4*)x_bf + idx);  // read much later (final GEMM)
        ((bf16x4*)x_s)[idx] = s;                              // gathered soon: keep cached
        return;
    }
    int j = idx - CAST_N4;
    if (j < 32768) {                       // W1t[n*128+k] = W1[k*256+n]
        int n = j >> 7, k = j & 127;
        W1t[j] = (__bf16)W1[k * 256 + n];
    } else if (j < 32768 + 65536) {        // W2t[n*256+k] = W2[k*256+n]
        int i = j - 32768;
        int n = i >> 8, k = i & 255;
        W2t[i] = (__bf16)W2[k * 256 + n];
    } else if (j < 32768 + 65536 + 16384) {  // Wft[n*256+k] = Wf[k*64+n]
        int i = j - (32768 + 65536);
        int n = i >> 8, k = i & 255;
        Wft[i] = (__bf16)Wf[k * 64 + n];
    } else if (j < 32768 + 65536 + 16384 + 8192) {  // Wst[n*128+k] = Ws[k*64+n]
        int i = j - (32768 + 65536 + 16384);
        int n = i >> 7, k = i & 127;
        Wst[i] = (__bf16)Ws[k * 64 + n];
    } else if (j < 32768 + 65536 + 16384 + 8192 + 64) {
        int i = j - (32768 + 65536 + 16384 + 8192);
        bfinal[i] = bfb[i] + bsb[i];
    }
}

// ---------------- aggregation: out[i] = dinv[i]*(in_s[i] + sum_e in_s[s]) ----------------
// Half-wave layout: 32 lanes cover one row; each load instruction gathers TWO
// edges' rows. Unroll 8 edges/iter = 4 KB in flight per wave. shfl_xor(32) merge.

template <int V> struct VecSel;
template <> struct VecSel<4> { using T = bf16x4; };
template <> struct VecSel<8> { using T = bf16x8; };

template <int F>
__global__ __launch_bounds__(256) void aggregate_half(const __bf16* __restrict__ in_s, __bf16* __restrict__ out,
                                                      const int* __restrict__ rowptr, const int* __restrict__ csr_src,
                                                      const float* __restrict__ dinv) {
    constexpr int VB = F / 32;  // elems per lane within a half-wave row
    using VT = typename VecSel<VB>::T;
    int node = blockIdx.x * 4 + (threadIdx.x >> 6);
    int lane = threadIdx.x & 63;
    int lh = lane & 31;
    int half = lane >> 5;
    const __bf16* colbase = in_s + (size_t)lh * VB;

    float acc[VB] = {};
    if (half == 0) {  // self-loop row loaded by half A only
        VT v = *(const VT*)(colbase + (size_t)node * F);
#pragma unroll
        for (int j = 0; j < VB; ++j) acc[j] = (float)v[j];
    }

    int beg = rowptr[node], end = rowptr[node + 1];
    int e = beg;
    for (; e + 8 <= end; e += 8) {
        int a0 = csr_src[e + 0], a1 = csr_src[e + 1], a2 = csr_src[e + 2], a3 = csr_src[e + 3];
        int a4 = csr_src[e + 4], a5 = csr_src[e + 5], a6 = csr_src[e + 6], a7 = csr_src[e + 7];
        int s0 = half ? a1 : a0, s1 = half ? a3 : a2, s2 = half ? a5 : a4, s3 = half ? a7 : a6;
        VT v0 = *(const VT*)(colbase + (size_t)s0 * F);
        VT v1 = *(const VT*)(colbase + (size_t)s1 * F);
        VT v2 = *(const VT*)(colbase + (size_t)s2 * F);
        VT v3 = *(const VT*)(colbase + (size_t)s3 * F);
#pragma unroll
        for (int j = 0; j < VB; ++j) {
            acc[j] += (float)v0[j];
            acc[j] += (float)v1[j];
            acc[j] += (float)v2[j];
            acc[j] += (float)v3[j];
        }
    }
    for (; e + 2 <= end; e += 2) {
        int a0 = csr_src[e], a1 = csr_src[e + 1];
        int s = half ? a1 : a0;
        VT v = *(const VT*)(colbase + (size_t)s * F);
#pragma unroll
        for (int j = 0; j < VB; ++j) acc[j] += (float)v[j];
    }
    if (e < end && half == 0) {  // odd tail: half A only
        int s = csr_src[e];
        VT v = *(const VT*)(colbase + (size_t)s * F);
#pragma unroll
        for (int j = 0; j < VB; ++j) acc[j] += (float)v[j];
    }

    float di = dinv[node];
    VT o;
#pragma unroll
    for (int j = 0; j < VB; ++j) {
        float t = acc[j] + __shfl_xor(acc[j], 32);
        o[j] = (__bf16)(di * t);
    }
    // nt: do not evict gather-resident lines for the output stream
    if (half == 0) __builtin_nontemporal_store(o, (VT*)(out + (size_t)node * F + lh * VB));
}

// ---------------- MFMA bf16 GEMM staging (shared) ----------------
// LDS rows of 64 bf16 (8 x 16B granules), granule slot XOR-swizzled with (row&7).
// global_load_lds writes linearly; global SOURCE address pre-swizzled with the same
// involution so the swizzled read matches (rule 21).

template <int NROWS, int NTH>
__device__ __forceinline__ void stage_tile(const __bf16* __restrict__ src, int K, int row0, int rowclamp,
                                           int k0, char* lds) {
    int t = threadIdx.x;
#pragma unroll
    for (int p = 0; p < NROWS * 8 / NTH; ++p) {
        int G = p * NTH + t;
        int r = G >> 3, gp = G & 7;
        int g = gp ^ (r & 7);
        int gr = row0 + r;
        if (gr > rowclamp) gr = rowclamp;
        const __bf16* sp = src + (size_t)gr * K + k0 + g * 8;
        __builtin_amdgcn_global_load_lds((const __attribute__((address_space(1))) void*)sp,
                                         (__attribute__((address_space(3))) void*)(lds + G * 16), 16, 0, 0);
    }
}

// ---------------- wide GEMM: C[M x 256] = A[M x K] * Bt[256 x K]^T ----------------
// BM=64, 512 thr = 8 waves (1x8), wave tile 64x32, acc[4][2].
// launch_bounds(512,4): VGPR<=128 -> 2 blocks/CU resident (was 1 with acc[4][4]).

template <bool SCALE>
__global__ __launch_bounds__(512, 4) void mfma_gemm_wide(const __bf16* __restrict__ A, const __bf16* __restrict__ Bt,
                                                         int K, const float* __restrict__ bias,
                                                         const float* __restrict__ dinv,
                                                         __bf16* __restrict__ C, int M) {
    constexpr int N = 256;
    __shared__ alignas(16) char lds[40960];  // A: 64x64x2 = 8 KB, B: 256x64x2 = 32 KB
    char* As = lds;
    char* Bs = lds + 8192;
    const int lane = threadIdx.x & 63, wid = threadIdx.x >> 6;  // wid = wave col (0..7)
    const int row0 = blockIdx.x * 64;
    const int kg = lane >> 4, l15 = lane & 15;

    f32x4 acc[4][2];
#pragma unroll
    for (int mi = 0; mi < 4; ++mi)
#pragma unroll
        for (int ni = 0; ni < 2; ++ni) acc[mi][ni] = {0.f, 0.f, 0.f, 0.f};

    for (int k0 = 0; k0 < K; k0 += 64) {
        stage_tile<64, 512>(A, K, row0, M - 1, k0, As);
        stage_tile<256, 512>(Bt, K, 0, N - 1, k0, Bs);
        __syncthreads();
        bf16x8 af[4][2], bfr[2][2];
#pragma unroll
        for (int mi = 0; mi < 4; ++mi) {
            int r = mi * 16 + l15;
#pragma unroll
            for (int kf = 0; kf < 2; ++kf) {
                int slot = (kf * 4 + kg) ^ (r & 7);
                af[mi][kf] = *(const bf16x8*)(As + r * 128 + slot * 16);
            }
        }
#pragma unroll
        for (int ni = 0; ni < 2; ++ni) {
            int r = wid * 32 + ni * 16 + l15;
#pragma unroll
            for (int kf = 0; kf < 2; ++kf) {
                int slot = (kf * 4 + kg) ^ (r & 7);
                bfr[ni][kf] = *(const bf16x8*)(Bs + r * 128 + slot * 16);
            }
        }
#pragma unroll
        for (int mi = 0; mi < 4; ++mi)
#pragma unroll
            for (int ni = 0; ni < 2; ++ni)
#pragma unroll
                for (int kf = 0; kf < 2; ++kf)
                    acc[mi][ni] = __builtin_amdgcn_mfma_f32_16x16x32_bf16(af[mi][kf], bfr[ni][kf],
                                                                          acc[mi][ni], 0, 0, 0);
        __syncthreads();
    }

    // C/D layout: col = lane&15, row = (lane>>4)*4 + q
#pragma unroll
    for (int mi = 0; mi < 4; ++mi) {
#pragma unroll
        for (int q = 0; q < 4; ++q) {
            int gr = row0 + mi * 16 + kg * 4 + q;
            if (gr >= M) continue;
            float sc = SCALE ? dinv[gr] : 1.0f;
#pragma unroll
            for (int ni = 0; ni < 2; ++ni) {
                int col = wid * 32 + ni * 16 + l15;
                float v = acc[mi][ni][q] + bias[col];
                v = fmaxf(v, 0.f);  // both uses are relu layers
                if (SCALE) v *= sc;
                C[(size_t)gr * N + col] = (__bf16)v;
            }
        }
    }
}

// ---------------- final GEMM: out[M x 64] = A1*B1t^T + A2*B2t^T + bias (f32 out) ----------------
// BM=64, 256 thr = 4 waves (2x2), wave tile 32x32, acc[2][2]; 4 blocks/CU.

__global__ __launch_bounds__(256, 4) void mfma_gemm_final(const __bf16* __restrict__ A1, const __bf16* __restrict__ B1t, int K1,
                                                          const __bf16* __restrict__ A2, const __bf16* __restrict__ B2t, int K2,
                                                          const float* __restrict__ bias, float* __restrict__ Cout, int M) {
    constexpr int N = 64;
    __shared__ alignas(16) char lds[16384];  // A: 64x64x2 = 8 KB, B: 64x64x2 = 8 KB
    char* As = lds;
    char* Bs = lds + 8192;
    const int lane = threadIdx.x & 63, wid = threadIdx.x >> 6;
    const int wm = wid >> 1, wn = wid & 1;
    const int row0 = blockIdx.x * 64;
    const int kg = lane >> 4, l15 = lane & 15;

    f32x4 acc[2][2];
#pragma unroll
    for (int mi = 0; mi < 2; ++mi)
#pragma unroll
        for (int ni = 0; ni < 2; ++ni) acc[mi][ni] = {0.f, 0.f, 0.f, 0.f};

    auto run_K = [&](const __bf16* A, const __bf16* Bt, int K) {
        for (int k0 = 0; k0 < K; k0 += 64) {
            stage_tile<64, 256>(A, K, row0, M - 1, k0, As);
            stage_tile<64, 256>(Bt, K, 0, N - 1, k0, Bs);
            __syncthreads();
            bf16x8 af[2][2], bfr[2][2];
#pragma unroll
            for (int mi = 0; mi < 2; ++mi) {
                int r = wm * 32 + mi * 16 + l15;
#pragma unroll
                for (int kf = 0; kf < 2; ++kf) {
                    int slot = (kf * 4 + kg) ^ (r & 7);
                    af[mi][kf] = *(const bf16x8*)(As + r * 128 + slot * 16);
                }
            }
#pragma unroll
            for (int ni = 0; ni < 2; ++ni) {
                int r = wn * 32 + ni * 16 + l15;
#pragma unroll
                for (int kf = 0; kf < 2; ++kf) {
                    int slot = (kf * 4 + kg) ^ (r & 7);
                    bfr[ni][kf] = *(const bf16x8*)(Bs + r * 128 + slot * 16);
                }
            }
#pragma unroll
            for (int mi = 0; mi < 2; ++mi)
#pragma unroll
                for (int ni = 0; ni < 2; ++ni)
#pragma unroll
                    for (int kf = 0; kf < 2; ++kf)
                        acc[mi][ni] = __builtin_amdgcn_mfma_f32_16x16x32_bf16(af[mi][kf], bfr[ni][kf],
                                                                              acc[mi][ni], 0, 0, 0);
            __syncthreads();
        }
    };
    run_K(A1, B1t, K1);
    run_K(A2, B2t, K2);

#pragma unroll
    for (int mi = 0; mi < 2; ++mi) {
#pragma unroll
        for (int ni = 0; ni < 2; ++ni) {
            int col = wn * 32 + ni * 16 + l15;
            float bv = bias[col];
#pragma unroll
            for (int q = 0; q < 4; ++q) {
                int gr = row0 + wm * 32 + mi * 16 + kg * 4 + q;
                if (gr < M) Cout[(size_t)gr * N + col] = acc[mi][ni][q] + bv;
            }
        }
    }
}

// ---------------- launch ----------------

extern "C" void kernel_launch(void* const* d_in, const int* in_sizes, int n_in,
                              void* d_out, int out_size, void* d_ws, size_t ws_size,
                              hipStream_t stream) {
    const float* x  = (const float*)d_in[0];
    const int*   ei = (const int*)d_in[1];
    const int*   src = ei;
    const int*   dst = ei + N_EDGES;
    const float* W1 = (const float*)d_in[2];
    const float* b1 = (const float*)d_in[3];
    const float* W2 = (const float*)d_in[4];
    const float* b2 = (const float*)d_in[5];
    const float* Wf = (const float*)d_in[6];
    const float* bf = (const float*)d_in[7];
    const float* Ws = (const float*)d_in[8];
    const float* bs = (const float*)d_in[9];
    float* out = (float*)d_out;

    char* ws = (char*)d_ws;
    size_t off = 0;
    auto alloc = [&](size_t bytes) -> void* {
        void* p = ws + off;
        off += (bytes + 255) & ~(size_t)255;
        return p;
    };
    int*     deg      = (int*)alloc(N_NODES * 4);   // adjacent to cursor: one memset covers both
    int*     cursor   = (int*)alloc(N_NODES * 4);
    int*     rowptr   = (int*)alloc((N_NODES + 1) * 4);
    float*   dinv     = (float*)alloc(N_NODES * 4);
    int*     blocksum = (int*)alloc(4096);
    int*     csr      = (int*)alloc(N_EDGES * 4);
    __bf16*  x_bf     = (__bf16*)alloc((size_t)N_NODES * 128 * 2);  // unscaled (skip GEMM)
    __bf16*  x_s      = (__bf16*)alloc((size_t)N_NODES * 128 * 2);  // dinv-scaled (agg1 input)
    __bf16*  W1t      = (__bf16*)alloc(128 * 256 * 2);
    __bf16*  W2t      = (__bf16*)alloc(256 * 256 * 2);
    __bf16*  Wft      = (__bf16*)alloc(256 * 64 * 2);
    __bf16*  Wst      = (__bf16*)alloc(128 * 64 * 2);
    float*   bfinal   = (float*)alloc(64 * 4);
    __bf16*  bufP1    = (__bf16*)alloc((size_t)N_NODES * 256 * 2);  // agg1 out (128-wide), later h2
    __bf16*  bufP2    = (__bf16*)alloc((size_t)N_NODES * 256 * 2);  // h1_s
    __bf16*  bufP3    = (__bf16*)alloc((size_t)N_NODES * 256 * 2);  // agg2 out

    // deg (200192 padded) + cursor (200192 padded) in one memset
    hipMemsetAsync(deg, 0, 200192 + 200192, stream);

    hist_kernel<<<(N_EDGES + 255) / 256, 256, 0, stream>>>(dst, deg, N_EDGES);

    int nb = (N_NODES + 511) / 512;  // 98
    scan_partial_dinv<<<nb, 512, 0, stream>>>(deg, N_NODES, rowptr, blocksum, dinv);
    scan_add_fused<<<nb, 512, 0, stream>>>(rowptr, N_NODES, blocksum, nb, N_EDGES);
    fill_csr<<<(N_EDGES + 255) / 256, 256, 0, stream>>>(src, dst, N_EDGES, rowptr, cursor, csr);

    const int prep_total = CAST_N4 + 32768 + 65536 + 16384 + 8192 + 64;
    cast_prep<<<(prep_total + 255) / 256, 256, 0, stream>>>(x, dinv, x_bf, x_s,
                                                            W1, W2, Wf, Ws, bf, bs,
                                                            W1t, W2t, Wft, Wst, bfinal);

    const int gm64 = (N_NODES + 63) / 64;  // 782

    // layer 1: agg1 = Ahat x (pre-scaled x_s); h1_s = dinv * relu(agg1 @ W1 + b1)
    aggregate_half<128><<<(N_NODES + 3) / 4, 256, 0, stream>>>(x_s, bufP1, rowptr, csr, dinv);
    mfma_gemm_wide<true><<<gm64, 512, 0, stream>>>(bufP1, W1t, 128, b1, dinv, bufP2, N_NODES);

    // layer 2: agg2 = dinv * (sum of h1_s + self); h2 = relu(agg2 @ W2 + b2)
    aggregate_half<256><<<(N_NODES + 3) / 4, 256, 0, stream>>>(bufP2, bufP3, rowptr, csr, dinv);
    mfma_gemm_wide<false><<<gm64, 512, 0, stream>>>(bufP3, W2t, 256, b2, nullptr, bufP1, N_NODES);

    // out = h2 @ Wf + x @ Ws + (bf + bs)
    mfma_gemm_final<<<gm64, 256, 0, stream>>>(bufP1, Wft, 256, x_bf, Wst, 128, bfinal, out, N_NODES);
}